// Round 7
// baseline (398.712 us; speedup 1.0000x reference)
//
#include <hip/hip_runtime.h>
#include <hip/hip_bf16.h>

// Problem constants (from reference)
#define B_   2
#define T_   2048
#define D_   2048
#define H_   16
#define KV_  4
#define HD_  128
#define BT_  (B_*T_)         // 4096 token rows
#define QKVP 3072            // per-token pitch of merged [q|k|v] buffer
#define KOFF 2048            // k segment offset within a token row
#define VOFF 2560            // v segment offset within a token row
static constexpr float EPS_ = 1e-6f;

typedef unsigned short u16;
typedef __attribute__((ext_vector_type(8))) short short8;          // 8 bf16 = 16 B
typedef __attribute__((ext_vector_type(4))) float f32x4;           // MFMA acc
typedef __attribute__((ext_vector_type(4))) unsigned short u16x4;  // 8 B

__device__ __forceinline__ u16 f2bf(float f){
    unsigned u = __float_as_uint(f);
    u += 0x7FFF + ((u >> 16) & 1);          // round-to-nearest-even
    return (u16)(u >> 16);
}
__device__ __forceinline__ float bf2f(u16 u){
    return __uint_as_float((unsigned)u << 16);
}

// Async global->LDS, 16 B per lane. LDS dest must be wave-uniform base + lane*16.
__device__ __forceinline__ void async_copy16(const void* g, void* l) {
    __builtin_amdgcn_global_load_lds(
        (const __attribute__((address_space(1))) unsigned int*)g,
        (__attribute__((address_space(3))) unsigned int*)l, 16, 0, 0);
}

// ---------------------------------------------------------------------------
// f32 -> bf16 elementwise convert (n % 4 == 0)
// ---------------------------------------------------------------------------
__global__ __launch_bounds__(256) void cvt_f32_bf16_kernel(
    const float* __restrict__ in, u16* __restrict__ out, int n)
{
    const int i = (blockIdx.x*256 + threadIdx.x)*4;
    if (i < n) {
        float4 v = *(const float4*)&in[i];
        u16x4 w = { f2bf(v.x), f2bf(v.y), f2bf(v.z), f2bf(v.w) };
        *(u16x4*)&out[i] = w;
    }
}

// ---------------------------------------------------------------------------
// Transpose + convert: in [R][C] f32  ->  out [C][R] bf16 (out pitch = R).
// ---------------------------------------------------------------------------
__global__ __launch_bounds__(256) void transpose_cvt_kernel(
    const float* __restrict__ in, u16* __restrict__ out, int R, int C)
{
    __shared__ u16 tile[64][65];
    const int r0 = blockIdx.y*64, c0 = blockIdx.x*64;
    const int tr = threadIdx.x >> 4;          // 0..15
    const int tc = (threadIdx.x & 15) * 4;    // 0,4,..60
    #pragma unroll
    for (int i = 0; i < 4; i++) {
        const int r = tr + i*16;
        float4 v = *(const float4*)&in[(size_t)(r0 + r)*C + c0 + tc];
        tile[tc+0][r] = f2bf(v.x);
        tile[tc+1][r] = f2bf(v.y);
        tile[tc+2][r] = f2bf(v.z);
        tile[tc+3][r] = f2bf(v.w);
    }
    __syncthreads();
    #pragma unroll
    for (int i = 0; i < 4; i++) {
        const int c = tr + i*16;
        u16x4 w = { tile[c][tc+0], tile[c][tc+1], tile[c][tc+2], tile[c][tc+3] };
        *(u16x4*)&out[(size_t)(c0 + c)*R + r0 + tc] = w;
    }
}

// ---------------------------------------------------------------------------
// bf16 transpose of the V segment of the merged qkv buffer:
//   in:  qkv[(b*T+t)*QKVP + VOFF + kvh*HD_ + d]
//   out: vt[((b*KV_+kvh)*HD_ + d)*T_ + t]
// ---------------------------------------------------------------------------
__global__ __launch_bounds__(256) void transpose_v_kernel(
    const u16* __restrict__ qkv, u16* __restrict__ vt)
{
    __shared__ u16 tile[64][65];
    const int t0 = blockIdx.x*64;
    const int d0 = blockIdx.y*64;              // 0 or 64
    const int bk = blockIdx.z;                 // b*KV_+kvh
    const int tr = threadIdx.x >> 4;           // 0..15
    const int tc = (threadIdx.x & 15) * 4;     // 0,4,..60
    #pragma unroll
    for (int i = 0; i < 4; i++) {
        const int t = t0 + tr + i*16;
        u16x4 v = *(const u16x4*)&qkv[(size_t)((bk>>2)*T_ + t)*QKVP + VOFF
                                      + (bk&3)*HD_ + d0 + tc];
        tile[tc+0][tr+i*16] = v[0];
        tile[tc+1][tr+i*16] = v[1];
        tile[tc+2][tr+i*16] = v[2];
        tile[tc+3][tr+i*16] = v[3];
    }
    __syncthreads();
    #pragma unroll
    for (int i = 0; i < 4; i++) {
        const int d = tr + i*16;
        u16x4 w = { tile[d][tc+0], tile[d][tc+1], tile[d][tc+2], tile[d][tc+3] };
        *(u16x4*)&vt[((size_t)bk*HD_ + d0 + d)*T_ + t0 + tc] = w;
    }
}

// ---------------------------------------------------------------------------
// m97-style MFMA GEMM with pitches: C[.,N] = A @ Bt^T, bf16 in, f32 acc.
// 128x128 tile, BK=32, 256 threads (4 waves, 2x2 quadrants of 64x64).
// ---------------------------------------------------------------------------
#define GBM 128
#define GBN 128
#define GBK 32

template<bool OUT_BF16>
__global__ __launch_bounds__(256) void gemm_mfma_kernel(
    const u16* __restrict__ A, const u16* __restrict__ Bt,
    void* __restrict__ C, int N, int K, int lda, int ldb, int ldc)
{
    __shared__ __align__(16) u16 As[GBM][GBK];
    __shared__ __align__(16) u16 Bs[GBN][GBK];
    const int tid  = threadIdx.x;
    const int lane = tid & 63;
    const int wave = tid >> 6;
    const int l15  = lane & 15;
    const int quad = lane >> 4;
    const int wr   = (wave >> 1) * 64;
    const int wc   = (wave & 1) * 64;
    const size_t row0 = (size_t)blockIdx.y * GBM;
    const size_t col0 = (size_t)blockIdx.x * GBN;

    f32x4 acc[4][4];
    #pragma unroll
    for (int i = 0; i < 4; i++)
        #pragma unroll
        for (int j = 0; j < 4; j++)
            acc[i][j] = (f32x4){0.f,0.f,0.f,0.f};

    for (int k0 = 0; k0 < K; k0 += GBK) {
        #pragma unroll
        for (int c = 0; c < 2; c++) {
            const int e = (c*256 + tid) * 8;
            const int r = e >> 5, cc = e & 31;
            async_copy16(A  + (row0 + r)*lda + k0 + cc, &As[r][cc]);
            async_copy16(Bt + (col0 + r)*ldb + k0 + cc, &Bs[r][cc]);
        }
        __syncthreads();

        short8 af[4], bf[4];
        #pragma unroll
        for (int i = 0; i < 4; i++)
            af[i] = *(const short8*)&As[wr + i*16 + l15][quad*8];
        #pragma unroll
        for (int j = 0; j < 4; j++)
            bf[j] = *(const short8*)&Bs[wc + j*16 + l15][quad*8];
        #pragma unroll
        for (int i = 0; i < 4; i++)
            #pragma unroll
            for (int j = 0; j < 4; j++)
                acc[i][j] = __builtin_amdgcn_mfma_f32_16x16x32_bf16(
                    af[i], bf[j], acc[i][j], 0, 0, 0);
        __syncthreads();
    }

    #pragma unroll
    for (int i = 0; i < 4; i++)
        #pragma unroll
        for (int r = 0; r < 4; r++) {
            const size_t row = row0 + wr + i*16 + quad*4 + r;
            #pragma unroll
            for (int j = 0; j < 4; j++) {
                const size_t col = col0 + wc + j*16 + l15;
                if (OUT_BF16) ((u16*)C)[row*ldc + col] = f2bf(acc[i][j][r]);
                else          ((float*)C)[row*ldc + col] = acc[i][j][r];
            }
        }
}

// ---------------------------------------------------------------------------
// Fused RMSNorm + RoPE, in place on bf16 rows inside the pitched qkv buffer.
// One WAVE per head-row: lane owns the interleaved RoPE pair (2l, 2l+1).
// ---------------------------------------------------------------------------
__global__ __launch_bounds__(256) void rmsnorm_rope_kernel(
    u16* __restrict__ qk, const float* __restrict__ scale,
    const float* __restrict__ cosT, const float* __restrict__ sinT,
    int heads_per_token, int head_off, float post_scale)
{
    const int wid   = blockIdx.x*4 + (threadIdx.x >> 6);   // global wave id = row
    const int lane  = threadIdx.x & 63;
    const int token = wid / heads_per_token;
    const int hidx  = wid % heads_per_token;
    const int t     = token & (T_ - 1);
    u16* p = qk + (size_t)token*QKVP + head_off + hidx*HD_ + lane*2;

    const unsigned u = *(const unsigned*)p;                // 2 bf16
    const float x0 = bf2f((u16)(u & 0xffff));
    const float x1 = bf2f((u16)(u >> 16));
    float ss = x0*x0 + x1*x1;
    #pragma unroll
    for (int off = 32; off > 0; off >>= 1) ss += __shfl_xor(ss, off);
    const float rms = rsqrtf(ss * (1.0f/HD_) + EPS_);

    const float2 sc = *(const float2*)&scale[lane*2];
    const float2 cs = *(const float2*)&cosT[(size_t)t*HD_ + lane*2];
    const float2 sn = *(const float2*)&sinT[(size_t)t*HD_ + lane*2];
    const float n0 = x0 * rms * sc.x;
    const float n1 = x1 * rms * sc.y;
    const float r0 = (n0*cs.x - n1*sn.x) * post_scale;
    const float r1 = (n1*cs.y + n0*sn.y) * post_scale;
    *(unsigned*)p = (unsigned)f2bf(r0) | ((unsigned)f2bf(r1) << 16);
}

// ---------------------------------------------------------------------------
// Flash-style causal GQA attention v10: SPLIT-K flash-decoding.
//  r2-r6 lessons: wall time = (max serial k-rounds per block) x L, with
//  L ~= 6.5K cy at 2-block/CU concurrency; traffic cuts and occupancy alone
//  don't move L. So cap the serial depth:
//    qt <= 18: whole chain in one block (depth <= 19), O written in place.
//    qt >= 19: chain split into two key-halves (depth <= 16); each half
//      writes PARTIAL O (f32) + row-sums into dead workspace (xb/Wqkvt
//      region, 27.5 MB). FIXED-MAX softmax makes partials ADDITIVE --
//      no max/rescale bookkeeping: O = (O_A+O_B)/(l_A+l_B).
//  Grid 45x16x2 = 1440 blocks, 4 resident/CU + 416 backfill (dynamic
//  balance). Deep blocks ordered first. Combine kernel merges the 416
//  split outputs. Full blocks write rows < 1216; half blocks read Q rows
//  >= 1216 -- disjoint, race-free.
// ---------------------------------------------------------------------------
#define BQ  64
#define BKV 64
#define QT_SPLIT 19          // chains with qt >= QT_SPLIT are split in two
#define NSPLIT   (32 - QT_SPLIT)             // 13 split qts
#define PSLOT    16512                       // per-(b,h,qt) partial f32s
#define PHALF    8256                        // per-half: 64*128 O + 64 lsum

__global__ __launch_bounds__(256, 4) void attn_mfma10_kernel(
    const u16* __restrict__ qkv, const u16* __restrict__ Vtg,
    float* __restrict__ part)
{
    __shared__ __align__(16) u16 Ks[16][BKV][8];   // [k-chunk][key][8]    16 KB
    __shared__ __align__(16) u16 Vt[8][HD_][8];    // [key-chunk][d][8]    16 KB
    __shared__ __align__(16) u16 Pb[4][8][16][8];  // [wave][key-chunk][row][8] 8 KB

    // ---- work decode: m 0..25 = halves of qt 31..19 (deep first),
    //      m 26..44 = full chains qt 18..0 ----
    const int m = blockIdx.x;
    int qt, t0, t1, half;
    bool full;
    if (m < 2*NSPLIT) {
        qt = 31 - (m >> 1);
        const int cnt = qt + 1;
        const int kA  = cnt - (cnt >> 1);
        half = m & 1;
        t0 = half ? kA : 0;
        t1 = half ? cnt : kA;
        full = false;
    } else {
        qt = 18 - (m - 2*NSPLIT);
        t0 = 0; t1 = qt + 1; half = 0;
        full = true;
    }

    const int h    = blockIdx.y;
    const int b    = blockIdx.z;
    const int kvh  = h >> 2;                       // H_/KV_ = 4
    const int tid  = threadIdx.x;
    const int lane = tid & 63;
    const int wave = tid >> 6;
    const int l15  = lane & 15;
    const int quad = lane >> 4;
    const int q0   = qt * BQ;

    // ---- Q A-fragments straight to registers (row = wave*16+l15) ----
    short8 qf[4];
    {
        const u16* qbase = qkv + (size_t)(b*T_ + q0 + wave*16 + l15)*QKVP + h*HD_;
        #pragma unroll
        for (int kt = 0; kt < 4; kt++)
            qf[kt] = *(const short8*)(qbase + (kt*4 + quad)*8);
    }

    float lsum[4] = {0.f, 0.f, 0.f, 0.f};          // per-lane partial row sums
    f32x4 oacc[8];
    #pragma unroll
    for (int cv = 0; cv < 8; cv++) oacc[cv] = (f32x4){0.f,0.f,0.f,0.f};

    for (int t = t0; t < t1; t++) {
        const int k0 = t * BKV;
        __syncthreads();        // all waves done reading prev K/V

        // ---- stage K tile [16cc][64key] from k segment ----
        #pragma unroll
        for (int it = 0; it < 4; it++) {
            const int n2  = it*256 + tid;
            const int cc  = n2 >> 6;
            const int key = n2 & 63;
            async_copy16(qkv + (size_t)(b*T_ + k0 + key)*QKVP + KOFF + kvh*HD_ + cc*8,
                         &Ks[cc][key][0]);
        }
        // ---- stage V^T tile [8cc][128d] ----
        #pragma unroll
        for (int it = 0; it < 4; it++) {
            const int n2 = it*256 + tid;
            const int cc = n2 >> 7;
            const int d  = n2 & 127;
            async_copy16(Vtg + ((size_t)(b*KV_ + kvh)*HD_ + d)*T_ + k0 + cc*8,
                         &Vt[cc][d][0]);
        }
        __syncthreads();        // drains vmcnt(0): staged data visible

        // ---- S = Q @ K^T : wave slab (16 rows) x 64 keys ----
        f32x4 s4[4];
        #pragma unroll
        for (int c = 0; c < 4; c++) s4[c] = (f32x4){0.f,0.f,0.f,0.f};
        __builtin_amdgcn_s_setprio(1);
        #pragma unroll
        for (int kt = 0; kt < 4; kt++) {
            #pragma unroll
            for (int c = 0; c < 4; c++) {
                short8 bf = *(const short8*)&Ks[kt*4 + quad][c*16 + l15][0];
                s4[c] = __builtin_amdgcn_mfma_f32_16x16x32_bf16(qf[kt], bf, s4[c], 0, 0, 0);
            }
        }
        __builtin_amdgcn_s_setprio(0);

        // ---- fixed-max softmax: mask (diag tile only), exp, partial sums ----
        if (t == qt) {
            const int qrow0 = q0 + wave*16 + quad*4;
            #pragma unroll
            for (int r = 0; r < 4; r++)
                #pragma unroll
                for (int c = 0; c < 4; c++) {
                    const int key = k0 + c*16 + l15;
                    if (key > qrow0 + r) s4[c][r] = -1e30f;
                }
        }
        #pragma unroll
        for (int r = 0; r < 4; r++)
            #pragma unroll
            for (int c = 0; c < 4; c++) {
                const float p = __expf(s4[c][r]);
                s4[c][r] = p;
                lsum[r] += p;
            }

        // ---- P -> wave-private LDS (A-operand layout), no barrier needed ----
        #pragma unroll
        for (int r = 0; r < 4; r++)
            #pragma unroll
            for (int c = 0; c < 4; c++)
                Pb[wave][c*2 + (l15 >> 3)][quad*4 + r][l15 & 7] = f2bf(s4[c][r]);

        // ---- O += P @ V (no rescale: fixed-max) ----
        __builtin_amdgcn_s_setprio(1);
        #pragma unroll
        for (int kt2 = 0; kt2 < 2; kt2++) {
            short8 a = *(const short8*)&Pb[wave][kt2*4 + quad][l15][0];
            #pragma unroll
            for (int cv = 0; cv < 8; cv++) {
                short8 vf = *(const short8*)&Vt[kt2*4 + quad][cv*16 + l15][0];
                oacc[cv] = __builtin_amdgcn_mfma_f32_16x16x32_bf16(a, vf, oacc[cv], 0, 0, 0);
            }
        }
        __builtin_amdgcn_s_setprio(0);
    }

    // ---- epilogue ----
    if (full) {
        // reduce row sums, divide, write O bf16 in place
        #pragma unroll
        for (int r = 0; r < 4; r++) {
            float tot = lsum[r];
            #pragma unroll
            for (int off = 1; off < 16; off <<= 1)
                tot += __shfl_xor(tot, off, 16);
            const float linv = 1.0f / tot;
            u16* orow = (u16*)qkv + (size_t)(b*T_ + q0 + wave*16 + quad*4 + r)*QKVP
                        + h*HD_ + l15;
            #pragma unroll
            for (int cv = 0; cv < 8; cv++)
                orow[cv*16] = f2bf(oacc[cv][r] * linv);
        }
    } else {
        // write raw partial O (f32) + row-sums; combine kernel merges
        float* po = part + (size_t)((b*H_ + h)*NSPLIT + (qt - QT_SPLIT))*PSLOT
                         + (size_t)half*PHALF;
        #pragma unroll
        for (int r = 0; r < 4; r++) {
            float tot = lsum[r];
            #pragma unroll
            for (int off = 1; off < 16; off <<= 1)
                tot += __shfl_xor(tot, off, 16);
            const int row = wave*16 + quad*4 + r;
            #pragma unroll
            for (int cv = 0; cv < 8; cv++)
                po[row*128 + cv*16 + l15] = oacc[cv][r];
            if (l15 == 0) po[8192 + row] = tot;
        }
    }
}

// ---------------------------------------------------------------------------
// Combine split-K halves: O = (O_A + O_B) / (l_A + l_B), bf16 into qkv.
// One block per split (b,h,qt); 256 threads over 64 rows x 128 cols.
// ---------------------------------------------------------------------------
__global__ __launch_bounds__(256) void attn_combine_kernel(
    const float* __restrict__ part, u16* __restrict__ qkv)
{
    const int p  = blockIdx.x;                 // 0..415
    const int qt = QT_SPLIT + (p % NSPLIT);
    const int bh = p / NSPLIT;
    const int h  = bh & 15;
    const int b  = bh >> 4;
    const float* p0 = part + (size_t)p*PSLOT;
    const float* p1 = p0 + PHALF;
    const int tid = threadIdx.x;
    const int row = tid >> 2;                  // 0..63
    const int c0  = (tid & 3) * 32;            // 0,32,64,96
    const float linv = 1.0f / (p0[8192 + row] + p1[8192 + row]);
    u16* orow = qkv + (size_t)(b*T_ + qt*BQ + row)*QKVP + h*HD_;
    #pragma unroll
    for (int d = 0; d < 32; d += 4) {
        const int col = c0 + d;
        u16x4 w = { f2bf((p0[row*128 + col+0] + p1[row*128 + col+0]) * linv),
                    f2bf((p0[row*128 + col+1] + p1[row*128 + col+1]) * linv),
                    f2bf((p0[row*128 + col+2] + p1[row*128 + col+2]) * linv),
                    f2bf((p0[row*128 + col+3] + p1[row*128 + col+3]) * linv) };
        *(u16x4*)&orow[col] = w;
    }
}

// ---------------------------------------------------------------------------
extern "C" void kernel_launch(void* const* d_in, const int* in_sizes, int n_in,
                              void* d_out, int out_size, void* d_ws, size_t ws_size,
                              hipStream_t stream)
{
    const float* x    = (const float*)d_in[0];   // [B,T,D]
    const float* Wq   = (const float*)d_in[1];   // [D, H*HD]
    const float* Wk   = (const float*)d_in[2];   // [D, KV*HD]
    const float* Wv   = (const float*)d_in[3];   // [D, KV*HD]
    const float* Wo   = (const float*)d_in[4];   // [H*HD, D]
    const float* qsc  = (const float*)d_in[5];   // [HD]
    const float* ksc  = (const float*)d_in[6];   // [HD]
    const float* cosT = (const float*)d_in[7];   // [T, HD]
    const float* sinT = (const float*)d_in[8];   // [T, HD]
    float* out = (float*)d_out;

    // Workspace carve (bf16, ~67 MB total)
    u16* xb     = (u16*)d_ws;                      // [BT, 2048]  (dead after proj)
    u16* Wqkvt  = xb    + (size_t)BT_*D_;          // [3072, 2048] (dead after proj)
    u16* Wot    = Wqkvt + (size_t)QKVP*D_;         // [2048, 2048]
    u16* qkv    = Wot   + (size_t)D_*(H_*HD_);     // [BT, 3072]
    u16* vtg    = qkv   + (size_t)BT_*QKVP;        // [B*KV, HD, T]
    // split-K partials reuse the dead xb+Wqkvt region (27.5 MB < 29.4 MB)
    float* part = (float*)d_ws;

    // ---- convert x; transpose+convert weights (concatenated qkv weight) ----
    cvt_f32_bf16_kernel<<<(BT_*D_)/1024, 256, 0, stream>>>(x, xb, BT_*D_);
    transpose_cvt_kernel<<<dim3((H_*HD_)/64,  D_/64), 256, 0, stream>>>(
        Wq, Wqkvt, D_, H_*HD_);
    transpose_cvt_kernel<<<dim3((KV_*HD_)/64, D_/64), 256, 0, stream>>>(
        Wk, Wqkvt + (size_t)KOFF*D_, D_, KV_*HD_);
    transpose_cvt_kernel<<<dim3((KV_*HD_)/64, D_/64), 256, 0, stream>>>(
        Wv, Wqkvt + (size_t)VOFF*D_, D_, KV_*HD_);
    transpose_cvt_kernel<<<dim3(D_/64, (H_*HD_)/64),  256, 0, stream>>>(
        Wo, Wot, H_*HD_, D_);

    // ---- merged q|k|v projection: [4096,2048] x [2048,3072] ----
    gemm_mfma_kernel<true><<<dim3(QKVP/GBN, BT_/GBM), 256, 0, stream>>>(
        xb, Wqkvt, qkv, QKVP, D_, D_, D_, QKVP);

    // ---- RMSNorm + RoPE in place (q gets 1/sqrt(HD) folded in) ----
    rmsnorm_rope_kernel<<<(BT_*H_)/4,  256, 0, stream>>>(
        qkv, qsc, cosT, sinT, H_, 0, 0.08838834764831845f);
    rmsnorm_rope_kernel<<<(BT_*KV_)/4, 256, 0, stream>>>(
        qkv, ksc, cosT, sinT, KV_, KOFF, 1.0f);

    // ---- V^T into global [b*KV][d][t] ----
    transpose_v_kernel<<<dim3(T_/64, HD_/64, B_*KV_), 256, 0, stream>>>(qkv, vtg);

    // ---- Flash attention v10: split-K, max serial depth 19, 1440 blocks ----
    attn_mfma10_kernel<<<dim3(19 + 2*NSPLIT, H_, B_), 256, 0, stream>>>(
        qkv, vtg, part);

    // ---- merge split halves (416 tiles) ----
    attn_combine_kernel<<<B_*H_*NSPLIT, 256, 0, stream>>>(part, qkv);

    // ---- out = attn @ Wo (f32 out): A = q segment, pitch 3072 ----
    gemm_mfma_kernel<false><<<dim3(D_/GBN, BT_/GBM), 256, 0, stream>>>(
        qkv, Wot, out, D_, D_, QKVP, D_, D_);
}

// Round 8
// 372.358 us; speedup vs baseline: 1.0708x; 1.0708x over previous
//
#include <hip/hip_runtime.h>
#include <hip/hip_bf16.h>

// Problem constants (from reference)
#define B_   2
#define T_   2048
#define D_   2048
#define H_   16
#define KV_  4
#define HD_  128
#define BT_  (B_*T_)         // 4096 token rows
#define QKVP 3072            // per-token pitch of merged [q|k|v] buffer
#define KOFF 2048            // k segment offset within a token row
#define VOFF 2560            // v segment offset within a token row
static constexpr float EPS_ = 1e-6f;

typedef unsigned short u16;
typedef __attribute__((ext_vector_type(8))) short short8;          // 8 bf16 = 16 B
typedef __attribute__((ext_vector_type(4))) float f32x4;           // MFMA acc
typedef __attribute__((ext_vector_type(4))) unsigned short u16x4;  // 8 B

__device__ __forceinline__ u16 f2bf(float f){
    unsigned u = __float_as_uint(f);
    u += 0x7FFF + ((u >> 16) & 1);          // round-to-nearest-even
    return (u16)(u >> 16);
}
__device__ __forceinline__ float bf2f(u16 u){
    return __uint_as_float((unsigned)u << 16);
}

// Async global->LDS, 16 B per lane. LDS dest must be wave-uniform base + lane*16.
__device__ __forceinline__ void async_copy16(const void* g, void* l) {
    __builtin_amdgcn_global_load_lds(
        (const __attribute__((address_space(1))) unsigned int*)g,
        (__attribute__((address_space(3))) unsigned int*)l, 16, 0, 0);
}

// ---------------------------------------------------------------------------
// f32 -> bf16 elementwise convert (n % 4 == 0)
// ---------------------------------------------------------------------------
__global__ __launch_bounds__(256) void cvt_f32_bf16_kernel(
    const float* __restrict__ in, u16* __restrict__ out, int n)
{
    const int i = (blockIdx.x*256 + threadIdx.x)*4;
    if (i < n) {
        float4 v = *(const float4*)&in[i];
        u16x4 w = { f2bf(v.x), f2bf(v.y), f2bf(v.z), f2bf(v.w) };
        *(u16x4*)&out[i] = w;
    }
}

// ---------------------------------------------------------------------------
// Transpose + convert: in [R][C] f32  ->  out [C][R] bf16 (out pitch = R).
// ---------------------------------------------------------------------------
__global__ __launch_bounds__(256) void transpose_cvt_kernel(
    const float* __restrict__ in, u16* __restrict__ out, int R, int C)
{
    __shared__ u16 tile[64][65];
    const int r0 = blockIdx.y*64, c0 = blockIdx.x*64;
    const int tr = threadIdx.x >> 4;          // 0..15
    const int tc = (threadIdx.x & 15) * 4;    // 0,4,..60
    #pragma unroll
    for (int i = 0; i < 4; i++) {
        const int r = tr + i*16;
        float4 v = *(const float4*)&in[(size_t)(r0 + r)*C + c0 + tc];
        tile[tc+0][r] = f2bf(v.x);
        tile[tc+1][r] = f2bf(v.y);
        tile[tc+2][r] = f2bf(v.z);
        tile[tc+3][r] = f2bf(v.w);
    }
    __syncthreads();
    #pragma unroll
    for (int i = 0; i < 4; i++) {
        const int c = tr + i*16;
        u16x4 w = { tile[c][tc+0], tile[c][tc+1], tile[c][tc+2], tile[c][tc+3] };
        *(u16x4*)&out[(size_t)(c0 + c)*R + r0 + tc] = w;
    }
}

// ---------------------------------------------------------------------------
// bf16 transpose of the V segment of the merged qkv buffer:
//   in:  qkv[(b*T+t)*QKVP + VOFF + kvh*HD_ + d]
//   out: vt[((b*KV_+kvh)*HD_ + d)*T_ + t]
// ---------------------------------------------------------------------------
__global__ __launch_bounds__(256) void transpose_v_kernel(
    const u16* __restrict__ qkv, u16* __restrict__ vt)
{
    __shared__ u16 tile[64][65];
    const int t0 = blockIdx.x*64;
    const int d0 = blockIdx.y*64;              // 0 or 64
    const int bk = blockIdx.z;                 // b*KV_+kvh
    const int tr = threadIdx.x >> 4;           // 0..15
    const int tc = (threadIdx.x & 15) * 4;     // 0,4,..60
    #pragma unroll
    for (int i = 0; i < 4; i++) {
        const int t = t0 + tr + i*16;
        u16x4 v = *(const u16x4*)&qkv[(size_t)((bk>>2)*T_ + t)*QKVP + VOFF
                                      + (bk&3)*HD_ + d0 + tc];
        tile[tc+0][tr+i*16] = v[0];
        tile[tc+1][tr+i*16] = v[1];
        tile[tc+2][tr+i*16] = v[2];
        tile[tc+3][tr+i*16] = v[3];
    }
    __syncthreads();
    #pragma unroll
    for (int i = 0; i < 4; i++) {
        const int d = tr + i*16;
        u16x4 w = { tile[d][tc+0], tile[d][tc+1], tile[d][tc+2], tile[d][tc+3] };
        *(u16x4*)&vt[((size_t)bk*HD_ + d0 + d)*T_ + t0 + tc] = w;
    }
}

// ---------------------------------------------------------------------------
// m97-style MFMA GEMM with pitches: C[.,N] = A @ Bt^T, bf16 in, f32 acc.
// 128x128 tile, BK=32, 256 threads (4 waves, 2x2 quadrants of 64x64).
// ---------------------------------------------------------------------------
#define GBM 128
#define GBN 128
#define GBK 32

template<bool OUT_BF16>
__global__ __launch_bounds__(256) void gemm_mfma_kernel(
    const u16* __restrict__ A, const u16* __restrict__ Bt,
    void* __restrict__ C, int N, int K, int lda, int ldb, int ldc)
{
    __shared__ __align__(16) u16 As[GBM][GBK];
    __shared__ __align__(16) u16 Bs[GBN][GBK];
    const int tid  = threadIdx.x;
    const int lane = tid & 63;
    const int wave = tid >> 6;
    const int l15  = lane & 15;
    const int quad = lane >> 4;
    const int wr   = (wave >> 1) * 64;
    const int wc   = (wave & 1) * 64;
    const size_t row0 = (size_t)blockIdx.y * GBM;
    const size_t col0 = (size_t)blockIdx.x * GBN;

    f32x4 acc[4][4];
    #pragma unroll
    for (int i = 0; i < 4; i++)
        #pragma unroll
        for (int j = 0; j < 4; j++)
            acc[i][j] = (f32x4){0.f,0.f,0.f,0.f};

    for (int k0 = 0; k0 < K; k0 += GBK) {
        #pragma unroll
        for (int c = 0; c < 2; c++) {
            const int e = (c*256 + tid) * 8;
            const int r = e >> 5, cc = e & 31;
            async_copy16(A  + (row0 + r)*lda + k0 + cc, &As[r][cc]);
            async_copy16(Bt + (col0 + r)*ldb + k0 + cc, &Bs[r][cc]);
        }
        __syncthreads();

        short8 af[4], bf[4];
        #pragma unroll
        for (int i = 0; i < 4; i++)
            af[i] = *(const short8*)&As[wr + i*16 + l15][quad*8];
        #pragma unroll
        for (int j = 0; j < 4; j++)
            bf[j] = *(const short8*)&Bs[wc + j*16 + l15][quad*8];
        #pragma unroll
        for (int i = 0; i < 4; i++)
            #pragma unroll
            for (int j = 0; j < 4; j++)
                acc[i][j] = __builtin_amdgcn_mfma_f32_16x16x32_bf16(
                    af[i], bf[j], acc[i][j], 0, 0, 0);
        __syncthreads();
    }

    #pragma unroll
    for (int i = 0; i < 4; i++)
        #pragma unroll
        for (int r = 0; r < 4; r++) {
            const size_t row = row0 + wr + i*16 + quad*4 + r;
            #pragma unroll
            for (int j = 0; j < 4; j++) {
                const size_t col = col0 + wc + j*16 + l15;
                if (OUT_BF16) ((u16*)C)[row*ldc + col] = f2bf(acc[i][j][r]);
                else          ((float*)C)[row*ldc + col] = acc[i][j][r];
            }
        }
}

// ---------------------------------------------------------------------------
// Fused RMSNorm + RoPE, in place on bf16 rows inside the pitched qkv buffer.
// One WAVE per head-row: lane owns the interleaved RoPE pair (2l, 2l+1).
// ---------------------------------------------------------------------------
__global__ __launch_bounds__(256) void rmsnorm_rope_kernel(
    u16* __restrict__ qk, const float* __restrict__ scale,
    const float* __restrict__ cosT, const float* __restrict__ sinT,
    int heads_per_token, int head_off, float post_scale)
{
    const int wid   = blockIdx.x*4 + (threadIdx.x >> 6);   // global wave id = row
    const int lane  = threadIdx.x & 63;
    const int token = wid / heads_per_token;
    const int hidx  = wid % heads_per_token;
    const int t     = token & (T_ - 1);
    u16* p = qk + (size_t)token*QKVP + head_off + hidx*HD_ + lane*2;

    const unsigned u = *(const unsigned*)p;                // 2 bf16
    const float x0 = bf2f((u16)(u & 0xffff));
    const float x1 = bf2f((u16)(u >> 16));
    float ss = x0*x0 + x1*x1;
    #pragma unroll
    for (int off = 32; off > 0; off >>= 1) ss += __shfl_xor(ss, off);
    const float rms = rsqrtf(ss * (1.0f/HD_) + EPS_);

    const float2 sc = *(const float2*)&scale[lane*2];
    const float2 cs = *(const float2*)&cosT[(size_t)t*HD_ + lane*2];
    const float2 sn = *(const float2*)&sinT[(size_t)t*HD_ + lane*2];
    const float n0 = x0 * rms * sc.x;
    const float n1 = x1 * rms * sc.y;
    const float r0 = (n0*cs.x - n1*sn.x) * post_scale;
    const float r1 = (n1*cs.y + n0*sn.y) * post_scale;
    *(unsigned*)p = (unsigned)f2bf(r0) | ((unsigned)f2bf(r1) << 16);
}

// ---------------------------------------------------------------------------
// Flash-style causal GQA attention v11 = v7 (r3 kernel, measured 90 us)
// + XOR-SWIZZLED P exchange (the one change; discriminating A/B for the
//   LDS-pipe-bound theory).
//  r7 synthesis: per-CU time == resident block-rounds x ~3.2K cy across ALL
//  five variants -> shared-pipe cap. LDS pipe accounting: ~2.3K cy/round in
//  v6/v9/v10; v7 cut traffic 1.47x but its P-read was an 8-way bank
//  conflict (pitch 88 u16 = 44 dwords; lanes i,i+8 alias) costing ~1.1K
//  cy/round -- exactly cancelling. Fix: col ^= (row&7)<<3 on both sides
//  (G4). Bank check: rows i,i+8 share XOR but their stride 352 dwords == 0
//  mod 32 -> 2-way (free, m136); quads hit distinct banks. 16B alignment
//  preserved (XOR on u16-index bits 3..5); bijective within the 64-col row.
//  Everything else byte-identical to the r3-passing kernel: wave (rh,kh)
//  owns 32 q-rows x key/d-half, paired q-tiles, dbuf K/V staging, lgkm-only
//  mid barrier, fixed-max softmax, per-key-half sums via SumX.
// ---------------------------------------------------------------------------
#define BQ  64
#define BKV 64

__global__ __launch_bounds__(256, 2) void attn_mfma11_kernel(
    const u16* __restrict__ qkv, const u16* __restrict__ Vtg)
{
    __shared__ __align__(16) u16 Ks[2][16][BKV][8];   // [buf][k-chunk][key][8] 32 KB
    __shared__ __align__(16) u16 Vt[2][8][HD_][8];    // [buf][key-chunk][d][8] 32 KB
    __shared__ __align__(16) u16 Pb[64][88];          // P exchange, padded   11 KB
    __shared__ float SumX[2][64];                     // per-key-half row sums

    const int pr   = blockIdx.x;                   // pair index 0..15
    const int h    = blockIdx.y;
    const int b    = blockIdx.z;
    const int kvh  = h >> 2;                       // H_/KV_ = 4
    const int tid  = threadIdx.x;
    const int lane = tid & 63;
    const int wave = tid >> 6;
    const int rh   = wave >> 1;                    // q-row half (0/1)
    const int kh   = wave & 1;                     // key half (QK^T) / d half (PV)
    const int l15  = lane & 15;
    const int quad = lane >> 4;
    const int NT   = T_ / BQ;                      // 32

    for (int phase = 0; phase < 2; phase++) {
        const int qt = phase ? pr : (NT - 1 - pr); // heavy tile first
        const int q0 = qt * BQ;

        // ---- Q A-fragments (32 rows: rh*32 + rf*16 + l15) ----
        short8 qf[2][4];
        #pragma unroll
        for (int rf = 0; rf < 2; rf++) {
            const u16* qbase = qkv + (size_t)(b*T_ + q0 + rh*32 + rf*16 + l15)*QKVP + h*HD_;
            #pragma unroll
            for (int kt = 0; kt < 4; kt++)
                qf[rf][kt] = *(const short8*)(qbase + kt*32 + quad*8);
        }

        float lsum[2][4];
        #pragma unroll
        for (int rf = 0; rf < 2; rf++)
            #pragma unroll
            for (int r = 0; r < 4; r++) lsum[rf][r] = 0.f;
        f32x4 oacc[2][4];
        #pragma unroll
        for (int rf = 0; rf < 2; rf++)
            #pragma unroll
            for (int cv = 0; cv < 4; cv++) oacc[rf][cv] = (f32x4){0.f,0.f,0.f,0.f};

        const int ntiles = qt + 1;

        // ---- prologue: stage tile 0 into buf 0 ----
        #pragma unroll
        for (int it = 0; it < 4; it++) {
            const int n   = it*256 + tid;
            const int cc  = n >> 6;
            const int key = n & 63;
            async_copy16(qkv + (size_t)(b*T_ + key)*QKVP + KOFF + kvh*HD_ + cc*8,
                         &Ks[0][cc][key][0]);
        }
        #pragma unroll
        for (int it = 0; it < 4; it++) {
            const int n  = it*256 + tid;
            const int cc = n >> 7;
            const int d  = n & 127;
            async_copy16(Vtg + ((size_t)(b*KV_ + kvh)*HD_ + d)*T_ + cc*8,
                         &Vt[0][cc][d][0]);
        }
        __syncthreads();   // drains vmcnt(0): tile 0 visible

        int cur = 0;
        for (int t = 0; t < ntiles; t++) {
            // ---- issue prefetch of tile t+1 into buf cur^1 (async) ----
            if (t + 1 < ntiles) {
                const int k0n = (t + 1) * BKV;
                #pragma unroll
                for (int it = 0; it < 4; it++) {
                    const int n   = it*256 + tid;
                    const int cc  = n >> 6;
                    const int key = n & 63;
                    async_copy16(qkv + (size_t)(b*T_ + k0n + key)*QKVP + KOFF + kvh*HD_ + cc*8,
                                 &Ks[cur^1][cc][key][0]);
                }
                #pragma unroll
                for (int it = 0; it < 4; it++) {
                    const int n  = it*256 + tid;
                    const int cc = n >> 7;
                    const int d  = n & 127;
                    async_copy16(Vtg + ((size_t)(b*KV_ + kvh)*HD_ + d)*T_ + k0n + cc*8,
                                 &Vt[cur^1][cc][d][0]);
                }
            }

            const int k0 = t * BKV;

            // ---- S quadrant = Q(32 rows) @ K^T(32-key half) ----
            f32x4 s[2][2];
            #pragma unroll
            for (int rf = 0; rf < 2; rf++)
                #pragma unroll
                for (int cj = 0; cj < 2; cj++) s[rf][cj] = (f32x4){0.f,0.f,0.f,0.f};
            __builtin_amdgcn_s_setprio(1);
            #pragma unroll
            for (int kt = 0; kt < 4; kt++) {
                #pragma unroll
                for (int cj = 0; cj < 2; cj++) {
                    short8 kf = *(const short8*)&Ks[cur][kt*4 + quad][kh*32 + cj*16 + l15][0];
                    #pragma unroll
                    for (int rf = 0; rf < 2; rf++)
                        s[rf][cj] = __builtin_amdgcn_mfma_f32_16x16x32_bf16(
                            qf[rf][kt], kf, s[rf][cj], 0, 0, 0);
                }
            }
            __builtin_amdgcn_s_setprio(0);

            // ---- fixed-max softmax: mask (diag tile only), exp, partials ----
            if (t == ntiles - 1) {
                #pragma unroll
                for (int rf = 0; rf < 2; rf++) {
                    const int qrow0 = q0 + rh*32 + rf*16 + quad*4;
                    #pragma unroll
                    for (int r = 0; r < 4; r++)
                        #pragma unroll
                        for (int cj = 0; cj < 2; cj++) {
                            const int key = k0 + kh*32 + cj*16 + l15;
                            if (key > qrow0 + r) s[rf][cj][r] = -1e30f;
                        }
                }
            }
            #pragma unroll
            for (int rf = 0; rf < 2; rf++)
                #pragma unroll
                for (int r = 0; r < 4; r++)
                    #pragma unroll
                    for (int cj = 0; cj < 2; cj++) {
                        const float p = __expf(s[rf][cj][r]);
                        s[rf][cj][r] = p;
                        lsum[rf][r] += p;
                        const int prow = rh*32 + rf*16 + quad*4 + r;
                        const int pcol = kh*32 + cj*16 + l15;
                        Pb[prow][pcol ^ ((prow & 7) << 3)] = f2bf(p);   // XOR swizzle
                    }

            // ---- mid barrier: publish P; lgkm-only so prefetch (vmcnt)
            //      stays in flight across it ----
            asm volatile("s_waitcnt lgkmcnt(0)" ::: "memory");
            __builtin_amdgcn_s_barrier();

            // ---- O(32 rows x 64-d half) += P(rows, all 64 keys) @ V ----
            __builtin_amdgcn_s_setprio(1);
            #pragma unroll
            for (int kt2 = 0; kt2 < 2; kt2++) {
                short8 pa[2];
                #pragma unroll
                for (int rf = 0; rf < 2; rf++) {
                    const int prow = rh*32 + rf*16 + l15;
                    const int pcol = (kt2*32 + quad*8) ^ ((prow & 7) << 3); // XOR swizzle
                    pa[rf] = *(const short8*)&Pb[prow][pcol];
                }
                #pragma unroll
                for (int cv = 0; cv < 4; cv++) {
                    short8 vf = *(const short8*)&Vt[cur][kt2*4 + quad][kh*64 + cv*16 + l15][0];
                    #pragma unroll
                    for (int rf = 0; rf < 2; rf++)
                        oacc[rf][cv] = __builtin_amdgcn_mfma_f32_16x16x32_bf16(
                            pa[rf], vf, oacc[rf][cv], 0, 0, 0);
                }
            }
            __builtin_amdgcn_s_setprio(0);

            // end-of-round barrier: drains prefetch (vmcnt 0) + protects
            // Ks/Vt buffer swap and Pb reuse.
            __syncthreads();
            cur ^= 1;
        }

        // ---- epilogue: combine key-half row sums, divide, write O ----
        #pragma unroll
        for (int rf = 0; rf < 2; rf++)
            #pragma unroll
            for (int r = 0; r < 4; r++) {
                float tot = lsum[rf][r];
                #pragma unroll
                for (int off = 1; off < 16; off <<= 1)
                    tot += __shfl_xor(tot, off, 16);
                if (l15 == 0) SumX[kh][rh*32 + rf*16 + quad*4 + r] = tot;
            }
        __syncthreads();
        #pragma unroll
        for (int rf = 0; rf < 2; rf++)
            #pragma unroll
            for (int r = 0; r < 4; r++) {
                const int rIdx = rh*32 + rf*16 + quad*4 + r;
                const float linv = 1.0f / (SumX[0][rIdx] + SumX[1][rIdx]);
                u16* orow = (u16*)qkv + (size_t)(b*T_ + q0 + rIdx)*QKVP
                            + h*HD_ + kh*64 + l15;
                #pragma unroll
                for (int cv = 0; cv < 4; cv++)
                    orow[cv*16] = f2bf(oacc[rf][cv][r] * linv);
            }
        __syncthreads();   // SumX/O settled before next phase reuses LDS
    }
}

// ---------------------------------------------------------------------------
extern "C" void kernel_launch(void* const* d_in, const int* in_sizes, int n_in,
                              void* d_out, int out_size, void* d_ws, size_t ws_size,
                              hipStream_t stream)
{
    const float* x    = (const float*)d_in[0];   // [B,T,D]
    const float* Wq   = (const float*)d_in[1];   // [D, H*HD]
    const float* Wk   = (const float*)d_in[2];   // [D, KV*HD]
    const float* Wv   = (const float*)d_in[3];   // [D, KV*HD]
    const float* Wo   = (const float*)d_in[4];   // [H*HD, D]
    const float* qsc  = (const float*)d_in[5];   // [HD]
    const float* ksc  = (const float*)d_in[6];   // [HD]
    const float* cosT = (const float*)d_in[7];   // [T, HD]
    const float* sinT = (const float*)d_in[8];   // [T, HD]
    float* out = (float*)d_out;

    // Workspace carve (bf16, ~67 MB total)
    u16* xb     = (u16*)d_ws;                      // [BT, 2048]
    u16* Wqkvt  = xb    + (size_t)BT_*D_;          // [3072, 2048]
    u16* Wot    = Wqkvt + (size_t)QKVP*D_;         // [2048, 2048]
    u16* qkv    = Wot   + (size_t)D_*(H_*HD_);     // [BT, 3072]
    u16* vtg    = qkv   + (size_t)BT_*QKVP;        // [B*KV, HD, T]

    // ---- convert x; transpose+convert weights (concatenated qkv weight) ----
    cvt_f32_bf16_kernel<<<(BT_*D_)/1024, 256, 0, stream>>>(x, xb, BT_*D_);
    transpose_cvt_kernel<<<dim3((H_*HD_)/64,  D_/64), 256, 0, stream>>>(
        Wq, Wqkvt, D_, H_*HD_);
    transpose_cvt_kernel<<<dim3((KV_*HD_)/64, D_/64), 256, 0, stream>>>(
        Wk, Wqkvt + (size_t)KOFF*D_, D_, KV_*HD_);
    transpose_cvt_kernel<<<dim3((KV_*HD_)/64, D_/64), 256, 0, stream>>>(
        Wv, Wqkvt + (size_t)VOFF*D_, D_, KV_*HD_);
    transpose_cvt_kernel<<<dim3(D_/64, (H_*HD_)/64),  256, 0, stream>>>(
        Wo, Wot, H_*HD_, D_);

    // ---- merged q|k|v projection: [4096,2048] x [2048,3072] ----
    gemm_mfma_kernel<true><<<dim3(QKVP/GBN, BT_/GBM), 256, 0, stream>>>(
        xb, Wqkvt, qkv, QKVP, D_, D_, D_, QKVP);

    // ---- RMSNorm + RoPE in place (q gets 1/sqrt(HD) folded in) ----
    rmsnorm_rope_kernel<<<(BT_*H_)/4,  256, 0, stream>>>(
        qkv, qsc, cosT, sinT, H_, 0, 0.08838834764831845f);
    rmsnorm_rope_kernel<<<(BT_*KV_)/4, 256, 0, stream>>>(
        qkv, ksc, cosT, sinT, KV_, KOFF, 1.0f);

    // ---- V^T into global [b*KV][d][t] ----
    transpose_v_kernel<<<dim3(T_/64, HD_/64, B_*KV_), 256, 0, stream>>>(qkv, vtg);

    // ---- Flash attention v11: v7 + conflict-free P exchange ----
    attn_mfma11_kernel<<<dim3(T_/BQ/2, H_, B_), 256, 0, stream>>>(qkv, vtg);

    // ---- out = attn @ Wo (f32 out): A = q segment, pitch 3072 ----
    gemm_mfma_kernel<false><<<dim3(D_/GBN, BT_/GBM), 256, 0, stream>>>(
        qkv, Wot, out, D_, D_, QKVP, D_, D_);
}